// Round 3
// baseline (8335.093 us; speedup 1.0000x reference)
//
#include <hip/hip_runtime.h>
#include <cstdint>
#include <cstddef>

#define DEV __device__ __forceinline__

typedef float  f32x2  __attribute__((ext_vector_type(2)));
typedef float  f32x4  __attribute__((ext_vector_type(4)));
typedef float  f32x16 __attribute__((ext_vector_type(16)));
typedef int    i32x2  __attribute__((ext_vector_type(2)));
typedef int    i32x4  __attribute__((ext_vector_type(4)));
typedef _Float16 f16x2 __attribute__((ext_vector_type(2)));
typedef _Float16 f16x8 __attribute__((ext_vector_type(8)));

constexpr float DT   = 0.5f;
constexpr float DT3  = 0.5f / 3.0f;   // dt/3
constexpr float DT23 = 1.0f / 3.0f;   // 2*dt/3
constexpr float DT8  = 0.0625f;       // dt/8

// scale-splits (keep MFMA operands out of fp16-subnormal range)
constexpr float S5  = 32.0f,   IS5 = 1.0f / 32.0f;
constexpr float S6  = 64.0f,   IS6 = 1.0f / 64.0f;
constexpr float S8  = 256.0f,  IS8 = 1.0f / 256.0f;
constexpr float S11 = 2048.0f;

// ---- LDS map (bytes) ----
// ACT region (49152): in-place chain  s(hi@0 [64][128]f16, lo*32@16384) ->
//   h1(hi@0 [64][256]f16, lo8*2048@32768 [64][256]fp8) -> h2(same) -> f(@0 [64][128]f32)
constexpr int ACT  = 0;
constexpr int SLO  = 16384;
constexpr int ALO  = 32768;
constexpr int W2L  = 49152;    // 65536: fp8 A-frag table W2_lo*2048
constexpr int W3L  = 114688;   // 32768: fp8 A-frag table W3_lo*2048
constexpr int B2O  = 147456;   // 1024
constexpr int B3O  = 148480;   // 512
constexpr int U01O = 148992;   // 2048
constexpr int SMEM_BYTES = 151040;

#define MFMA16(a, b, c) __builtin_amdgcn_mfma_f32_32x32x16_f16((a), (b), (c), 0, 0, 0)

DEV int swzb(int off, int m) { return off ^ ((m & 7) << 4); }

DEV float tanh_fast(float x) {
  float e = __builtin_amdgcn_exp2f(x * 2.885390082f);   // exp(2x)
  return 1.0f - 2.0f * __builtin_amdgcn_rcpf(e + 1.0f);
}

DEV unsigned pkh2(float a, float b) {
  f16x2 p = { (_Float16)a, (_Float16)b };
  return __builtin_bit_cast(unsigned, p);
}

DEV f16x8 read_f16t(const char* buf, int RS, int m, int kelem) {
  return *(const f16x8*)(buf + swzb(m * RS + kelem * 2, m));
}
DEV i32x2 read8b(const char* buf, int m, int kelem) {   // fp8 plane, RS=256B
  return *(const i32x2*)(buf + swzb(m * 256 + kelem, m));
}
DEV f16x8 mulh(f16x8 v, float s) {
  _Float16 h = (_Float16)s;
  f16x8 r;
#pragma unroll
  for (int j = 0; j < 8; ++j) r[j] = v[j] * h;
  return r;
}
// decode 8 fp8 (packed in i32x2) -> f16x8, scaled by sc
DEV f16x8 dec8(i32x2 r, float sc) {
  f32x2 p0 = __builtin_amdgcn_cvt_pk_f32_fp8(r[0], false);
  f32x2 p1 = __builtin_amdgcn_cvt_pk_f32_fp8(r[0], true);
  f32x2 p2 = __builtin_amdgcn_cvt_pk_f32_fp8(r[1], false);
  f32x2 p3 = __builtin_amdgcn_cvt_pk_f32_fp8(r[1], true);
  f16x2 q0 = __builtin_bit_cast(f16x2, __builtin_amdgcn_cvt_pkrtz(p0[0] * sc, p0[1] * sc));
  f16x2 q1 = __builtin_bit_cast(f16x2, __builtin_amdgcn_cvt_pkrtz(p1[0] * sc, p1[1] * sc));
  f16x2 q2 = __builtin_bit_cast(f16x2, __builtin_amdgcn_cvt_pkrtz(p2[0] * sc, p2[1] * sc));
  f16x2 q3 = __builtin_bit_cast(f16x2, __builtin_amdgcn_cvt_pkrtz(p3[0] * sc, p3[1] * sc));
  f16x8 o;
  o[0] = q0[0]; o[1] = q0[1]; o[2] = q1[0]; o[3] = q1[1];
  o[4] = q2[0]; o[5] = q2[1]; o[6] = q3[0]; o[7] = q3[1];
  return o;
}
// pack 4 floats (scaled) into 4 fp8 bytes
DEV int pk4fp8(float a, float b, float c, float d) {
  int w = __builtin_amdgcn_cvt_pk_fp8_f32(a, b, 0, false);
  w = __builtin_amdgcn_cvt_pk_fp8_f32(c, d, w, true);
  return w;
}

// split fp32x8 -> hi fp16 + lo*ls fp16
DEV void cvt_hl_s(const float* p, f16x8& hi, f16x8& lo, float ls) {
  f32x4 a = *(const f32x4*)p;
  f32x4 b = *(const f32x4*)(p + 4);
#pragma unroll
  for (int j = 0; j < 4; ++j) {
    _Float16 h = (_Float16)a[j]; hi[j] = h; lo[j] = (_Float16)((a[j] - (float)h) * ls);
    _Float16 g = (_Float16)b[j]; hi[4 + j] = g; lo[4 + j] = (_Float16)((b[j] - (float)g) * ls);
  }
}
DEV f16x8 cvt_h(const float* p) {
  f32x4 a = *(const f32x4*)p;
  f32x4 b = *(const f32x4*)(p + 4);
  f16x8 hi;
#pragma unroll
  for (int j = 0; j < 4; ++j) { hi[j] = (_Float16)a[j]; hi[4 + j] = (_Float16)b[j]; }
  return hi;
}

// write tanh(acc) as hi fp16 (@hi, RS512) + lo*2048 fp8 (@lo, RS256)
DEV void write_h8(char* hi, char* lo, f32x16 acc[2][2], int lane, int nbase) {
  const int mr = lane & 31, hh = lane >> 5;
#pragma unroll
  for (int nt = 0; nt < 2; ++nt)
#pragma unroll
    for (int mt = 0; mt < 2; ++mt) {
      int m = mt * 32 + mr;
#pragma unroll
      for (int g = 0; g < 4; ++g) {
        int n = nbase + nt * 32 + 8 * g + 4 * hh;
        float v0 = tanh_fast(acc[nt][mt][4 * g + 0]);
        float v1 = tanh_fast(acc[nt][mt][4 * g + 1]);
        float v2 = tanh_fast(acc[nt][mt][4 * g + 2]);
        float v3 = tanh_fast(acc[nt][mt][4 * g + 3]);
        i32x2 w;
        w[0] = (int)pkh2(v0, v1);
        w[1] = (int)pkh2(v2, v3);
        *(i32x2*)(hi + swzb(m * 512 + n * 2, m)) = w;
        float l0 = (v0 - (float)(_Float16)v0) * S11;
        float l1 = (v1 - (float)(_Float16)v1) * S11;
        float l2 = (v2 - (float)(_Float16)v2) * S11;
        float l3 = (v3 - (float)(_Float16)v3) * S11;
        *(int*)(lo + swzb(m * 256 + n, m)) = pk4fp8(l0, l1, l2, l3);
      }
    }
}

// encoder: relu(acc) hi fp16 (@hi) + lo*ls fp16 (@lo), both RS512
DEV void write_h16(char* hi, char* lo, f32x16 acc[2][2], int lane, int nbase, float ls) {
  const int mr = lane & 31, hh = lane >> 5;
#pragma unroll
  for (int nt = 0; nt < 2; ++nt)
#pragma unroll
    for (int mt = 0; mt < 2; ++mt) {
      int m = mt * 32 + mr;
#pragma unroll
      for (int g = 0; g < 4; ++g) {
        int n = nbase + nt * 32 + 8 * g + 4 * hh;
        float v0 = fmaxf(acc[nt][mt][4 * g + 0], 0.f);
        float v1 = fmaxf(acc[nt][mt][4 * g + 1], 0.f);
        float v2 = fmaxf(acc[nt][mt][4 * g + 2], 0.f);
        float v3 = fmaxf(acc[nt][mt][4 * g + 3], 0.f);
        i32x2 w;
        w[0] = (int)pkh2(v0, v1); w[1] = (int)pkh2(v2, v3);
        *(i32x2*)(hi + swzb(m * 512 + n * 2, m)) = w;
        w[0] = (int)pkh2((v0 - (float)(_Float16)v0) * ls, (v1 - (float)(_Float16)v1) * ls);
        w[1] = (int)pkh2((v2 - (float)(_Float16)v2) * ls, (v3 - (float)(_Float16)v3) * ls);
        *(i32x2*)(lo + swzb(m * 512 + n * 2, m)) = w;
      }
    }
}

// classifier: relu(acc) hi fp16 only
DEV void write_hc(char* hi, f32x16 acc[2][2], int lane, int nbase) {
  const int mr = lane & 31, hh = lane >> 5;
#pragma unroll
  for (int nt = 0; nt < 2; ++nt)
#pragma unroll
    for (int mt = 0; mt < 2; ++mt) {
      int m = mt * 32 + mr;
#pragma unroll
      for (int g = 0; g < 4; ++g) {
        int n = nbase + nt * 32 + 8 * g + 4 * hh;
        i32x2 w;
        w[0] = (int)pkh2(fmaxf(acc[nt][mt][4 * g + 0], 0.f), fmaxf(acc[nt][mt][4 * g + 1], 0.f));
        w[1] = (int)pkh2(fmaxf(acc[nt][mt][4 * g + 2], 0.f), fmaxf(acc[nt][mt][4 * g + 3], 0.f));
        *(i32x2*)(hi + swzb(m * 512 + n * 2, m)) = w;
      }
    }
}

// fp32 D[n][m] -> f layout [64][128]f32 RS512 @ACT
DEV void write_f32v(char* dst, const f32x16& a0, const f32x16& a1, int lane, int nbase) {
  const int mr = lane & 31, hh = lane >> 5;
#pragma unroll
  for (int mt = 0; mt < 2; ++mt) {
    const f32x16& a = mt ? a1 : a0;
    int m = mt * 32 + mr;
#pragma unroll
    for (int g = 0; g < 4; ++g) {
      int n = nbase + 8 * g + 4 * hh;
      f32x4 v = { a[4 * g + 0], a[4 * g + 1], a[4 * g + 2], a[4 * g + 3] };
      *(f32x4*)(dst + swzb(m * 512 + n * 4, m)) = v;
    }
  }
}

DEV void read_kv(const char* sm, int m, int cs, float* kv) {
#pragma unroll
  for (int blk = 0; blk < 8; ++blk) {
    f32x4 v = *(const f32x4*)(sm + ACT + swzb(m * 512 + cs * 128 + blk * 16, m));
    kv[4 * blk] = v[0]; kv[4 * blk + 1] = v[1]; kv[4 * blk + 2] = v[2]; kv[4 * blk + 3] = v[3];
  }
}

// owners: write 8 staged values: hi fp16 @ACT, lo*32 fp16 @SLO
DEV void write_stage8(char* sm, int m, int cs, int gg, const float* sv) {
  i32x4 wh, wl;
#pragma unroll
  for (int j = 0; j < 4; ++j) {
    float v0 = sv[2 * j], v1 = sv[2 * j + 1];
    _Float16 h0 = (_Float16)v0, h1 = (_Float16)v1;
    f16x2 ph = { h0, h1 };
    f16x2 pl = { (_Float16)((v0 - (float)h0) * S5), (_Float16)((v1 - (float)h1) * S5) };
    wh[j] = __builtin_bit_cast(int, ph);
    wl[j] = __builtin_bit_cast(int, pl);
  }
  int off = swzb(m * 256 + cs * 64 + gg * 16, m);
  *(i32x4*)(sm + ACT + off) = wh;
  *(i32x4*)(sm + SLO + off) = wl;
}

// ---- one MLP eval: s (ACT/SLO) -> f (ACT, fp32). 7 internal barriers ----
DEV void f_eval(char* sm, const f16x8* wsW1, float t,
                const f16x8* W1h, const f16x8* Au,
                const f16x8* W2f, const f16x8* W3f,
                int lane, int wave) {
  const int mr = lane & 31, kh = (lane >> 5) * 8, hh = lane >> 5;
  const int wb64 = wave * 64, wb32 = wave * 32;

  __syncthreads();  // A: stage visible
  f32x16 a1[2][2];
#pragma unroll
  for (int nt = 0; nt < 2; ++nt)
#pragma unroll
    for (int mt = 0; mt < 2; ++mt)
#pragma unroll
      for (int r = 0; r < 16; ++r) a1[nt][mt][r] = 0.f;

  // W1_lo stream (values *256 fp16, frag table in d_ws), depth-2 prefetch
  const f16x8* wp = wsW1 + (size_t)wave * 1024 + lane;   // + (nt*512 + ks*64)
  f16x8 wq[4][2];
  wq[0][0] = wp[0];   wq[0][1] = wp[512];
  wq[1][0] = wp[64];  wq[1][1] = wp[512 + 64];
#pragma unroll
  for (int ks = 0; ks < 8; ++ks) {
    if (ks < 6) {
      wq[(ks + 2) & 3][0] = wp[(ks + 2) * 64];
      wq[(ks + 2) & 3][1] = wp[512 + (ks + 2) * 64];
    }
    int ke = ks * 16 + kh;
    f16x8 bh0 = read_f16t(sm + ACT, 256, mr, ke);
    f16x8 bh1 = read_f16t(sm + ACT, 256, 32 + mr, ke);
    f16x8 bl0 = read_f16t(sm + SLO, 256, mr, ke);       // s_lo*32
    f16x8 bl1 = read_f16t(sm + SLO, 256, 32 + mr, ke);
    f16x8 bh0m = mulh(bh0, IS8), bh1m = mulh(bh1, IS8); // for W1_lo(*256) term
    f16x8 w1s0 = mulh(W1h[ks], IS5), w1s1 = mulh(W1h[8 + ks], IS5);
    // term1: s_hi @ W1_hi
    a1[0][0] = MFMA16(W1h[ks],     bh0, a1[0][0]);
    a1[0][1] = MFMA16(W1h[ks],     bh1, a1[0][1]);
    a1[1][0] = MFMA16(W1h[8 + ks], bh0, a1[1][0]);
    a1[1][1] = MFMA16(W1h[8 + ks], bh1, a1[1][1]);
    // term2: (s_lo*32) @ (W1_hi/32)
    a1[0][0] = MFMA16(w1s0, bl0, a1[0][0]);
    a1[0][1] = MFMA16(w1s0, bl1, a1[0][1]);
    a1[1][0] = MFMA16(w1s1, bl0, a1[1][0]);
    a1[1][1] = MFMA16(w1s1, bl1, a1[1][1]);
    // term3: (s_hi/256) @ (W1_lo*256)
    a1[0][0] = MFMA16(wq[ks & 3][0], bh0m, a1[0][0]);
    a1[0][1] = MFMA16(wq[ks & 3][0], bh1m, a1[0][1]);
    a1[1][0] = MFMA16(wq[ks & 3][1], bh0m, a1[1][0]);
    a1[1][1] = MFMA16(wq[ks & 3][1], bh1m, a1[1][1]);
  }
  // U-slice: U0 + t*U1 at ~fp32 (lo slots pre-scaled *256)
  {
    _Float16 th = (_Float16)t;
    _Float16 tl = (_Float16)(t - (float)th);
    f16x8 ub, ul;
#pragma unroll
    for (int j = 0; j < 8; ++j) { ub[j] = (_Float16)0.f; ul[j] = (_Float16)0.f; }
    if (kh == 0) {
      ub[0] = (_Float16)1.0f; ub[1] = th;
      ub[2] = (_Float16)IS8;  ub[3] = (_Float16)((float)th * IS8);
      ul[1] = tl;             ul[3] = (_Float16)((float)tl * IS8);
    }
#pragma unroll
    for (int nt = 0; nt < 2; ++nt) {
      a1[nt][0] = MFMA16(Au[nt], ub, a1[nt][0]);
      a1[nt][1] = MFMA16(Au[nt], ub, a1[nt][1]);
      a1[nt][0] = MFMA16(Au[nt], ul, a1[nt][0]);
      a1[nt][1] = MFMA16(Au[nt], ul, a1[nt][1]);
    }
  }
  __syncthreads();  // G1: s reads done
  write_h8(sm + ACT, sm + ALO, a1, lane, wb64);
  __syncthreads();  // C: h1 ready

  // ---- layer 2 ----
  const float* B2p = (const float*)(sm + B2O);
  f32x16 a2[2][2];
#pragma unroll
  for (int nt = 0; nt < 2; ++nt)
#pragma unroll
    for (int g = 0; g < 4; ++g) {
      int n = wb64 + nt * 32 + 8 * g + 4 * hh;
      f32x4 bv = *(const f32x4*)(B2p + n);
#pragma unroll
      for (int r = 0; r < 4; ++r) { a2[nt][0][4 * g + r] = bv[r]; a2[nt][1][4 * g + r] = bv[r]; }
    }
#pragma unroll
  for (int ks = 0; ks < 16; ++ks) {
    int ke = ks * 16 + kh;
    f16x8 bh0 = read_f16t(sm + ACT, 512, mr, ke);
    f16x8 bh1 = read_f16t(sm + ACT, 512, 32 + mr, ke);
    f16x8 bl0 = dec8(read8b(sm + ALO, mr, ke), IS6);      // h1_lo*32
    f16x8 bl1 = dec8(read8b(sm + ALO, 32 + mr, ke), IS6);
    f16x8 w2s0 = mulh(W2f[ks], IS5), w2s1 = mulh(W2f[16 + ks], IS5);
    f16x8 bh0m = mulh(bh0, IS6), bh1m = mulh(bh1, IS6);
    i32x2 t0 = *(const i32x2*)(sm + W2L + ((size_t)((wave * 2 + 0) * 16 + ks) * 64 + lane) * 8);
    i32x2 t1 = *(const i32x2*)(sm + W2L + ((size_t)((wave * 2 + 1) * 16 + ks) * 64 + lane) * 8);
    f16x8 wa0 = dec8(t0, IS5), wa1 = dec8(t1, IS5);       // W2_lo*64
    a2[0][0] = MFMA16(W2f[ks],      bh0, a2[0][0]);
    a2[0][1] = MFMA16(W2f[ks],      bh1, a2[0][1]);
    a2[1][0] = MFMA16(W2f[16 + ks], bh0, a2[1][0]);
    a2[1][1] = MFMA16(W2f[16 + ks], bh1, a2[1][1]);
    a2[0][0] = MFMA16(w2s0, bl0, a2[0][0]);
    a2[0][1] = MFMA16(w2s0, bl1, a2[0][1]);
    a2[1][0] = MFMA16(w2s1, bl0, a2[1][0]);
    a2[1][1] = MFMA16(w2s1, bl1, a2[1][1]);
    a2[0][0] = MFMA16(wa0, bh0m, a2[0][0]);
    a2[0][1] = MFMA16(wa0, bh1m, a2[0][1]);
    a2[1][0] = MFMA16(wa1, bh0m, a2[1][0]);
    a2[1][1] = MFMA16(wa1, bh1m, a2[1][1]);
  }
  __syncthreads();  // G2: h1 reads done
  write_h8(sm + ACT, sm + ALO, a2, lane, wb64);
  __syncthreads();  // E: h2 ready

  // ---- layer 3 ----
  const float* B3p = (const float*)(sm + B3O);
  f32x16 a30, a31;
#pragma unroll
  for (int g = 0; g < 4; ++g) {
    int n = wb32 + 8 * g + 4 * hh;
    f32x4 bv = *(const f32x4*)(B3p + n);
#pragma unroll
    for (int r = 0; r < 4; ++r) { a30[4 * g + r] = bv[r]; a31[4 * g + r] = bv[r]; }
  }
#pragma unroll
  for (int ks = 0; ks < 16; ++ks) {
    int ke = ks * 16 + kh;
    f16x8 bh0 = read_f16t(sm + ACT, 512, mr, ke);
    f16x8 bh1 = read_f16t(sm + ACT, 512, 32 + mr, ke);
    f16x8 bl0 = dec8(read8b(sm + ALO, mr, ke), IS6);
    f16x8 bl1 = dec8(read8b(sm + ALO, 32 + mr, ke), IS6);
    f16x8 w3s = mulh(W3f[ks], IS5);
    f16x8 bh0m = mulh(bh0, IS6), bh1m = mulh(bh1, IS6);
    i32x2 t0 = *(const i32x2*)(sm + W3L + ((size_t)(wave * 16 + ks) * 64 + lane) * 8);
    f16x8 wa = dec8(t0, IS5);
    a30 = MFMA16(W3f[ks], bh0, a30);
    a31 = MFMA16(W3f[ks], bh1, a31);
    a30 = MFMA16(w3s, bl0, a30);
    a31 = MFMA16(w3s, bl1, a31);
    a30 = MFMA16(wa, bh0m, a30);
    a31 = MFMA16(wa, bh1m, a31);
  }
  __syncthreads();  // G3: h2 reads done
  write_f32v(sm + ACT, a30, a31, lane, wb32);
  __syncthreads();  // F: f ready
}

__global__ void prep_w1lo(const float* __restrict__ W1, _Float16* __restrict__ ws) {
  int i = blockIdx.x * 256 + threadIdx.x;   // 0..4095 frags
  int lane = i & 63, ks = (i >> 6) & 7, nt = (i >> 9) & 1, wave = (i >> 10) & 3;
  int row = wave * 64 + nt * 32 + (lane & 31);
  int col = ks * 16 + (lane >> 5) * 8;
  const float* p = W1 + (size_t)row * 128 + col;
  _Float16* o = ws + (size_t)i * 8;
#pragma unroll
  for (int j = 0; j < 8; ++j) {
    float w = p[j];
    _Float16 h = (_Float16)w;
    o[j] = (_Float16)((w - (float)h) * S8);
  }
}

__global__ __launch_bounds__(256, 1) void node_kernel(
    const float* __restrict__ traj,
    const float* __restrict__ We1, const float* __restrict__ be1,
    const float* __restrict__ We2, const float* __restrict__ be2,
    const float* __restrict__ wte, const float* __restrict__ bte,
    const float* __restrict__ W1,  const float* __restrict__ b1,
    const float* __restrict__ W2,  const float* __restrict__ b2,
    const float* __restrict__ W3,  const float* __restrict__ b3,
    const float* __restrict__ Wc1, const float* __restrict__ bc1,
    const float* __restrict__ Wc2, const float* __restrict__ bc2,
    const _Float16* __restrict__ wsW1h, float* __restrict__ out) {
  __shared__ __align__(16) char sm[SMEM_BYTES];
  const int tid  = threadIdx.x;
  const int lane = tid & 63, wave = tid >> 6;
  const int mr = lane & 31, kh = (lane >> 5) * 8, hh = lane >> 5;
  const int wb64 = wave * 64, wb32 = wave * 32;
  const int brow = blockIdx.x * 64;
  const f16x8* wsW1 = (const f16x8*)wsW1h;

  // ---- init: U0/U1 fold, bias tables ----
  {
    int n = tid;
    float u0 = b1[n], u1 = 0.f;
    const float* wr = W1 + n * 128;
    for (int k = 0; k < 128; ++k) { float w = wr[k]; u1 += wte[k] * w; u0 += bte[k] * w; }
    float* U = (float*)(sm + U01O);
    U[2 * n] = u0; U[2 * n + 1] = u1;
    ((float*)(sm + B2O))[n] = b2[n];
    if (n < 128) ((float*)(sm + B3O))[n] = b3[n];
  }

  // ---- resident hi weight fragments ----
  f16x8 W1h[16], W2f[32], W3f[16], Au[2];
#pragma unroll
  for (int nt = 0; nt < 2; ++nt)
#pragma unroll
    for (int ks = 0; ks < 8; ++ks)
      W1h[nt * 8 + ks] = cvt_h(W1 + (size_t)(wb64 + nt * 32 + mr) * 128 + ks * 16 + kh);
#pragma unroll
  for (int nt = 0; nt < 2; ++nt)
#pragma unroll
    for (int ks = 0; ks < 16; ++ks)
      W2f[nt * 16 + ks] = cvt_h(W2 + (size_t)(wb64 + nt * 32 + mr) * 256 + ks * 16 + kh);
#pragma unroll
  for (int ks = 0; ks < 16; ++ks)
    W3f[ks] = cvt_h(W3 + (size_t)(wb32 + mr) * 256 + ks * 16 + kh);

  __syncthreads();  // U01 ready

  // Au: rows n, slots [U0h, U1h, U0l*256, U1l*256]
#pragma unroll
  for (int nt = 0; nt < 2; ++nt) {
    f16x8 a;
#pragma unroll
    for (int j = 0; j < 8; ++j) a[j] = (_Float16)0.f;
    if (kh == 0) {
      const float* U = (const float*)(sm + U01O);
      int n = wb64 + nt * 32 + mr;
      float u0 = U[2 * n], u1 = U[2 * n + 1];
      _Float16 u0h = (_Float16)u0, u1h = (_Float16)u1;
      a[0] = u0h; a[1] = u1h;
      a[2] = (_Float16)((u0 - (float)u0h) * S8);
      a[3] = (_Float16)((u1 - (float)u1h) * S8);
    }
    Au[nt] = a;
  }

  const int m_own = tid >> 2, cs = tid & 3;

  // ---- encoder ----
  f32x16 ae[2][2];
#pragma unroll
  for (int nt = 0; nt < 2; ++nt)
#pragma unroll
    for (int mt = 0; mt < 2; ++mt)
#pragma unroll
      for (int r = 0; r < 16; ++r) ae[nt][mt][r] = 0.f;

  for (int c = 0; c < 3; ++c) {
    // stage x chunk: hi@ACT [64][256]f16, lo*64@W2L(scratch)
#pragma unroll
    for (int g = 0; g < 8; ++g) {
      const float* xp = traj + (size_t)(brow + m_own) * 7168 + c * 256 + cs * 64 + g * 8;
      f32x4 a = *(const f32x4*)xp;
      f32x4 b = *(const f32x4*)(xp + 4);
      i32x4 wh, wl;
#pragma unroll
      for (int j = 0; j < 2; ++j) {
        float v0 = a[2 * j], v1 = a[2 * j + 1];
        _Float16 h0 = (_Float16)v0, h1 = (_Float16)v1;
        f16x2 ph = { h0, h1 };
        f16x2 pl = { (_Float16)((v0 - (float)h0) * S6), (_Float16)((v1 - (float)h1) * S6) };
        wh[j] = __builtin_bit_cast(int, ph); wl[j] = __builtin_bit_cast(int, pl);
        float w0 = b[2 * j], w1 = b[2 * j + 1];
        _Float16 g0 = (_Float16)w0, g1 = (_Float16)w1;
        f16x2 qh = { g0, g1 };
        f16x2 ql = { (_Float16)((w0 - (float)g0) * S6), (_Float16)((w1 - (float)g1) * S6) };
        wh[2 + j] = __builtin_bit_cast(int, qh); wl[2 + j] = __builtin_bit_cast(int, ql);
      }
      int off = swzb(m_own * 512 + cs * 128 + g * 16, m_own);
      *(i32x4*)(sm + ACT + off) = wh;
      *(i32x4*)(sm + W2L + off) = wl;
    }
    __syncthreads();
#pragma unroll
    for (int ks = 0; ks < 16; ++ks) {
      int ke = ks * 16 + kh;
      f16x8 bh0 = read_f16t(sm + ACT, 512, mr, ke);
      f16x8 bh1 = read_f16t(sm + ACT, 512, 32 + mr, ke);
      f16x8 bl0 = read_f16t(sm + W2L, 512, mr, ke);
      f16x8 bl1 = read_f16t(sm + W2L, 512, 32 + mr, ke);
      f16x8 bh0m = mulh(bh0, IS6), bh1m = mulh(bh1, IS6);
#pragma unroll
      for (int nt = 0; nt < 2; ++nt) {
        f16x8 wh, wl;
        cvt_hl_s(We1 + (size_t)(wb64 + nt * 32 + mr) * 768 + c * 256 + ks * 16 + kh, wh, wl, S6);
        f16x8 whs = mulh(wh, IS6);
        ae[nt][0] = MFMA16(wh, bh0, ae[nt][0]);
        ae[nt][1] = MFMA16(wh, bh1, ae[nt][1]);
        ae[nt][0] = MFMA16(whs, bl0, ae[nt][0]);
        ae[nt][1] = MFMA16(whs, bl1, ae[nt][1]);
        ae[nt][0] = MFMA16(wl, bh0m, ae[nt][0]);
        ae[nt][1] = MFMA16(wl, bh1m, ae[nt][1]);
      }
    }
    __syncthreads();
  }
#pragma unroll
  for (int nt = 0; nt < 2; ++nt)
#pragma unroll
    for (int r = 0; r < 16; ++r) {
      int n = wb64 + nt * 32 + (r & 3) + 8 * (r >> 2) + 4 * hh;
      float bv = be1[n];
      ae[nt][0][r] += bv; ae[nt][1][r] += bv;
    }
  write_h16(sm + ACT, sm + W2L, ae, lane, wb64, S6);   // h_enc hi@ACT, lo*64@W2L
  __syncthreads();

  {
    f32x16 az0, az1;
#pragma unroll
    for (int r = 0; r < 16; ++r) { az0[r] = 0.f; az1[r] = 0.f; }
#pragma unroll
    for (int ks = 0; ks < 16; ++ks) {
      int ke = ks * 16 + kh;
      f16x8 bh0 = read_f16t(sm + ACT, 512, mr, ke);
      f16x8 bh1 = read_f16t(sm + ACT, 512, 32 + mr, ke);
      f16x8 bl0 = read_f16t(sm + W2L, 512, mr, ke);
      f16x8 bl1 = read_f16t(sm + W2L, 512, 32 + mr, ke);
      f16x8 bh0m = mulh(bh0, IS6), bh1m = mulh(bh1, IS6);
      f16x8 wh, wl;
      cvt_hl_s(We2 + (size_t)(wb32 + mr) * 256 + ks * 16 + kh, wh, wl, S6);
      f16x8 whs = mulh(wh, IS6);
      az0 = MFMA16(wh, bh0, az0);
      az1 = MFMA16(wh, bh1, az1);
      az0 = MFMA16(whs, bl0, az0);
      az1 = MFMA16(whs, bl1, az1);
      az0 = MFMA16(wl, bh0m, az0);
      az1 = MFMA16(wl, bh1m, az1);
    }
#pragma unroll
    for (int r = 0; r < 16; ++r) {
      int n = wb32 + (r & 3) + 8 * (r >> 2) + 4 * hh;
      float bv = be2[n];
      az0[r] += bv; az1[r] += bv;
    }
    __syncthreads();                    // h_enc reads done
    write_f32v(sm + ACT, az0, az1, lane, wb32);  // z0 in f layout
    __syncthreads();
  }

  // ---- owners pick up z0; write frame 0 ----
  float z[32], Acc[32], k1v[32], kv[32];
  read_kv(sm, m_own, cs, z);
  float* outz = out + 16384;
  {
    float* p = outz + (size_t)(brow + m_own) * 128 + cs * 32;
#pragma unroll
    for (int g = 0; g < 8; ++g) {
      f32x4 v = { z[4 * g], z[4 * g + 1], z[4 * g + 2], z[4 * g + 3] };
      *(f32x4*)(p + 4 * g) = v;
    }
  }

  // ---- fill W2_lo / W3_lo fp8 tables (*2048) ----
#pragma unroll
  for (int nt = 0; nt < 2; ++nt)
    for (int ks = 0; ks < 16; ++ks) {
      const float* p = W2 + (size_t)(wb64 + nt * 32 + mr) * 256 + ks * 16 + kh;
      float l[8];
#pragma unroll
      for (int j = 0; j < 8; ++j) { float w = p[j]; l[j] = (w - (float)(_Float16)w) * S11; }
      i32x2 wv;
      wv[0] = pk4fp8(l[0], l[1], l[2], l[3]);
      wv[1] = pk4fp8(l[4], l[5], l[6], l[7]);
      *(i32x2*)(sm + W2L + ((size_t)((wave * 2 + nt) * 16 + ks) * 64 + lane) * 8) = wv;
    }
  for (int ks = 0; ks < 16; ++ks) {
    const float* p = W3 + (size_t)(wb32 + mr) * 256 + ks * 16 + kh;
    float l[8];
#pragma unroll
    for (int j = 0; j < 8; ++j) { float w = p[j]; l[j] = (w - (float)(_Float16)w) * S11; }
    i32x2 wv;
    wv[0] = pk4fp8(l[0], l[1], l[2], l[3]);
    wv[1] = pk4fp8(l[4], l[5], l[6], l[7]);
    *(i32x2*)(sm + W3L + ((size_t)(wave * 16 + ks) * 64 + lane) * 8) = wv;
  }

  // ---- RK4 (3/8 rule), 54 steps ----
  for (int st = 0; st < 54; ++st) {
    float t0 = st * 0.5f;
    __syncthreads();  // H: f/z0 reads done; tables ready (st==0)
#pragma unroll
    for (int gg = 0; gg < 4; ++gg) write_stage8(sm, m_own, cs, gg, z + 8 * gg);  // s1 = z
    f_eval(sm, wsW1, t0, W1h, Au, W2f, W3f, lane, wave);          // k1
    read_kv(sm, m_own, cs, kv);
    __syncthreads();
#pragma unroll
    for (int gg = 0; gg < 4; ++gg) {
      float sv[8];
#pragma unroll
      for (int i = 0; i < 8; ++i) {
        int e = 8 * gg + i;
        Acc[e] = z[e] + DT8 * kv[e];
        sv[i] = z[e] + DT3 * kv[e];
        k1v[e] = kv[e];
      }
      write_stage8(sm, m_own, cs, gg, sv);
    }
    f_eval(sm, wsW1, t0 + DT3, W1h, Au, W2f, W3f, lane, wave);    // k2
    read_kv(sm, m_own, cs, kv);
    __syncthreads();
#pragma unroll
    for (int gg = 0; gg < 4; ++gg) {
      float sv[8];
#pragma unroll
      for (int i = 0; i < 8; ++i) {
        int e = 8 * gg + i;
        Acc[e] += 3.0f * DT8 * kv[e];
        sv[i] = z[e] + DT * kv[e] - DT3 * k1v[e];
        k1v[e] = k1v[e] - kv[e];   // d12
      }
      write_stage8(sm, m_own, cs, gg, sv);
    }
    f_eval(sm, wsW1, t0 + DT23, W1h, Au, W2f, W3f, lane, wave);   // k3
    read_kv(sm, m_own, cs, kv);
    __syncthreads();
#pragma unroll
    for (int gg = 0; gg < 4; ++gg) {
      float sv[8];
#pragma unroll
      for (int i = 0; i < 8; ++i) {
        int e = 8 * gg + i;
        Acc[e] += 3.0f * DT8 * kv[e];
        sv[i] = z[e] + DT * (k1v[e] + kv[e]);
      }
      write_stage8(sm, m_own, cs, gg, sv);
    }
    f_eval(sm, wsW1, t0 + DT, W1h, Au, W2f, W3f, lane, wave);     // k4
    read_kv(sm, m_own, cs, kv);
#pragma unroll
    for (int e = 0; e < 32; ++e) z[e] = Acc[e] + DT8 * kv[e];
    if (st & 1) {
      int frame = (st >> 1) + 1;
      float* p = outz + (size_t)frame * 2097152 + (size_t)(brow + m_own) * 128 + cs * 32;
#pragma unroll
      for (int g = 0; g < 8; ++g) {
        f32x4 v = { z[4 * g], z[4 * g + 1], z[4 * g + 2], z[4 * g + 3] };
        *(f32x4*)(p + 4 * g) = v;
      }
    }
  }

  // ---- classifier ----
  __syncthreads();  // f reads done
#pragma unroll
  for (int gg = 0; gg < 4; ++gg) write_stage8(sm, m_own, cs, gg, z + 8 * gg);
  __syncthreads();
  f32x16 ac[2][2];
#pragma unroll
  for (int nt = 0; nt < 2; ++nt)
#pragma unroll
    for (int r = 0; r < 16; ++r) {
      int n = wb64 + nt * 32 + (r & 3) + 8 * (r >> 2) + 4 * hh;
      float bv = bc1[n];
      ac[nt][0][r] = bv; ac[nt][1][r] = bv;
    }
#pragma unroll
  for (int ks = 0; ks < 8; ++ks) {
    int ke = ks * 16 + kh;
    f16x8 bh0 = read_f16t(sm + ACT, 256, mr, ke);
    f16x8 bh1 = read_f16t(sm + ACT, 256, 32 + mr, ke);
    f16x8 bl0 = read_f16t(sm + SLO, 256, mr, ke);     // zL_lo*32
    f16x8 bl1 = read_f16t(sm + SLO, 256, 32 + mr, ke);
#pragma unroll
    for (int nt = 0; nt < 2; ++nt) {
      f16x8 wh, wl;
      cvt_hl_s(Wc1 + (size_t)(wb64 + nt * 32 + mr) * 128 + ks * 16 + kh, wh, wl, 1.0f);
      f16x8 whs = mulh(wh, IS5);
      ac[nt][0] = MFMA16(wh, bh0, ac[nt][0]);
      ac[nt][1] = MFMA16(wh, bh1, ac[nt][1]);
      ac[nt][0] = MFMA16(whs, bl0, ac[nt][0]);
      ac[nt][1] = MFMA16(whs, bl1, ac[nt][1]);
      ac[nt][0] = MFMA16(wl, bh0, ac[nt][0]);
      ac[nt][1] = MFMA16(wl, bh1, ac[nt][1]);
    }
  }
  __syncthreads();  // s reads done
  write_hc(sm + ACT, ac, lane, wb64);
  __syncthreads();
  if (tid < 64) {
    float acc = bc2[0];
#pragma unroll 8
    for (int c0 = 0; c0 < 256; c0 += 8) {
      f16x8 hv = read_f16t(sm + ACT, 512, tid, c0);
#pragma unroll
      for (int j = 0; j < 8; ++j) acc += (float)hv[j] * Wc2[c0 + j];
    }
    out[brow + tid] = __builtin_amdgcn_rcpf(1.0f + __builtin_amdgcn_exp2f(-acc * 1.442695041f));
  }
}

extern "C" void kernel_launch(void* const* d_in, const int* in_sizes, int n_in,
                              void* d_out, int out_size, void* d_ws, size_t ws_size,
                              hipStream_t stream) {
  (void)in_sizes; (void)n_in; (void)out_size; (void)ws_size;
  const float* traj = (const float*)d_in[0];
  const float* We1  = (const float*)d_in[1];
  const float* be1  = (const float*)d_in[2];
  const float* We2  = (const float*)d_in[3];
  const float* be2  = (const float*)d_in[4];
  const float* wte  = (const float*)d_in[5];
  const float* bte  = (const float*)d_in[6];
  const float* W1   = (const float*)d_in[7];
  const float* b1   = (const float*)d_in[8];
  const float* W2   = (const float*)d_in[9];
  const float* b2   = (const float*)d_in[10];
  const float* W3   = (const float*)d_in[11];
  const float* b3   = (const float*)d_in[12];
  const float* Wc1  = (const float*)d_in[13];
  const float* bc1  = (const float*)d_in[14];
  const float* Wc2  = (const float*)d_in[15];
  const float* bc2  = (const float*)d_in[16];
  _Float16* wsW1 = (_Float16*)d_ws;
  hipLaunchKernelGGL(prep_w1lo, dim3(16), dim3(256), 0, stream, W1, wsW1);
  hipLaunchKernelGGL(node_kernel, dim3(256), dim3(256), 0, stream,
                     traj, We1, be1, We2, be2, wte, bte, W1, b1, W2, b2, W3, b3,
                     Wc1, bc1, Wc2, bc2, (const _Float16*)wsW1, (float*)d_out);
}

// Round 4
// 7953.471 us; speedup vs baseline: 1.0480x; 1.0480x over previous
//
#include <hip/hip_runtime.h>
#include <cstdint>
#include <cstddef>

#define DEV __device__ __forceinline__

typedef float  f32x2  __attribute__((ext_vector_type(2)));
typedef float  f32x4  __attribute__((ext_vector_type(4)));
typedef float  f32x16 __attribute__((ext_vector_type(16)));
typedef int    i32x2  __attribute__((ext_vector_type(2)));
typedef int    i32x4  __attribute__((ext_vector_type(4)));
typedef _Float16 f16x2 __attribute__((ext_vector_type(2)));
typedef _Float16 f16x8 __attribute__((ext_vector_type(8)));

constexpr float DT   = 0.5f;
constexpr float DT3  = 0.5f / 3.0f;   // dt/3
constexpr float DT23 = 1.0f / 3.0f;   // 2*dt/3
constexpr float DT8  = 0.0625f;       // dt/8

// scale-splits (keep MFMA operands out of fp16-subnormal range)
constexpr float S5  = 32.0f,   IS5 = 1.0f / 32.0f;
constexpr float S6  = 64.0f,   IS6 = 1.0f / 64.0f;
constexpr float S8  = 256.0f,  IS8 = 1.0f / 256.0f;
constexpr float S11 = 2048.0f;

// ---- LDS map (bytes) ----
// ACT region (49152): in-place chain  s(hi@0 [64][128]f16, lo*32@16384) ->
//   h1(hi@0 [64][256]f16, lo8*2048@32768 [64][256]fp8) -> h2(same) -> f(@0 [64][128]f32)
constexpr int ACT  = 0;
constexpr int SLO  = 16384;
constexpr int ALO  = 32768;
constexpr int W2L  = 49152;    // 65536: fp8 A-frag table W2_lo*2048
constexpr int W3L  = 114688;   // 32768: fp8 A-frag table W3_lo*2048
constexpr int B2O  = 147456;   // 1024
constexpr int B3O  = 148480;   // 512
constexpr int U01O = 148992;   // 2048
constexpr int SMEM_BYTES = 151040;

#define MFMA16(a, b, c) __builtin_amdgcn_mfma_f32_32x32x16_f16((a), (b), (c), 0, 0, 0)

DEV int swzb(int off, int m) { return off ^ ((m & 7) << 4); }

DEV float tanh_fast(float x) {
  float e = __builtin_amdgcn_exp2f(x * 2.885390082f);   // exp(2x)
  return 1.0f - 2.0f * __builtin_amdgcn_rcpf(e + 1.0f);
}

DEV unsigned pkh2(float a, float b) {
  f16x2 p = { (_Float16)a, (_Float16)b };
  return __builtin_bit_cast(unsigned, p);
}

DEV f16x8 read_f16t(const char* buf, int RS, int m, int kelem) {
  return *(const f16x8*)(buf + swzb(m * RS + kelem * 2, m));
}
DEV i32x2 read8b(const char* buf, int m, int kelem) {   // fp8 plane, RS=256B
  return *(const i32x2*)(buf + swzb(m * 256 + kelem, m));
}
DEV f16x8 mulh(f16x8 v, float s) {
  _Float16 h = (_Float16)s;
  f16x8 r;
#pragma unroll
  for (int j = 0; j < 8; ++j) r[j] = v[j] * h;
  return r;
}
// decode 8 fp8 (packed in i32x2) -> f16x8, scaled by sc
DEV f16x8 dec8(i32x2 r, float sc) {
  f32x2 p0 = __builtin_amdgcn_cvt_pk_f32_fp8(r[0], false);
  f32x2 p1 = __builtin_amdgcn_cvt_pk_f32_fp8(r[0], true);
  f32x2 p2 = __builtin_amdgcn_cvt_pk_f32_fp8(r[1], false);
  f32x2 p3 = __builtin_amdgcn_cvt_pk_f32_fp8(r[1], true);
  f16x2 q0 = __builtin_bit_cast(f16x2, __builtin_amdgcn_cvt_pkrtz(p0[0] * sc, p0[1] * sc));
  f16x2 q1 = __builtin_bit_cast(f16x2, __builtin_amdgcn_cvt_pkrtz(p1[0] * sc, p1[1] * sc));
  f16x2 q2 = __builtin_bit_cast(f16x2, __builtin_amdgcn_cvt_pkrtz(p2[0] * sc, p2[1] * sc));
  f16x2 q3 = __builtin_bit_cast(f16x2, __builtin_amdgcn_cvt_pkrtz(p3[0] * sc, p3[1] * sc));
  f16x8 o;
  o[0] = q0[0]; o[1] = q0[1]; o[2] = q1[0]; o[3] = q1[1];
  o[4] = q2[0]; o[5] = q2[1]; o[6] = q3[0]; o[7] = q3[1];
  return o;
}
// pack 4 floats (scaled) into 4 fp8 bytes
DEV int pk4fp8(float a, float b, float c, float d) {
  int w = __builtin_amdgcn_cvt_pk_fp8_f32(a, b, 0, false);
  w = __builtin_amdgcn_cvt_pk_fp8_f32(c, d, w, true);
  return w;
}

// split fp32x8 -> hi fp16 + lo*ls fp16
DEV void cvt_hl_s(const float* p, f16x8& hi, f16x8& lo, float ls) {
  f32x4 a = *(const f32x4*)p;
  f32x4 b = *(const f32x4*)(p + 4);
#pragma unroll
  for (int j = 0; j < 4; ++j) {
    _Float16 h = (_Float16)a[j]; hi[j] = h; lo[j] = (_Float16)((a[j] - (float)h) * ls);
    _Float16 g = (_Float16)b[j]; hi[4 + j] = g; lo[4 + j] = (_Float16)((b[j] - (float)g) * ls);
  }
}
DEV f16x8 cvt_h(const float* p) {
  f32x4 a = *(const f32x4*)p;
  f32x4 b = *(const f32x4*)(p + 4);
  f16x8 hi;
#pragma unroll
  for (int j = 0; j < 4; ++j) { hi[j] = (_Float16)a[j]; hi[4 + j] = (_Float16)b[j]; }
  return hi;
}
DEV f16x8 cvt8v(f32x4 a, f32x4 b) {
  f16x8 h;
#pragma unroll
  for (int j = 0; j < 4; ++j) { h[j] = (_Float16)a[j]; h[4 + j] = (_Float16)b[j]; }
  return h;
}

// write tanh(acc) as hi fp16 (@hi, RS512) + lo*2048 fp8 (@lo, RS256)
DEV void write_h8(char* hi, char* lo, f32x16 acc[2][2], int lane, int nbase) {
  const int mr = lane & 31, hh = lane >> 5;
#pragma unroll
  for (int nt = 0; nt < 2; ++nt)
#pragma unroll
    for (int mt = 0; mt < 2; ++mt) {
      int m = mt * 32 + mr;
#pragma unroll
      for (int g = 0; g < 4; ++g) {
        int n = nbase + nt * 32 + 8 * g + 4 * hh;
        float v0 = tanh_fast(acc[nt][mt][4 * g + 0]);
        float v1 = tanh_fast(acc[nt][mt][4 * g + 1]);
        float v2 = tanh_fast(acc[nt][mt][4 * g + 2]);
        float v3 = tanh_fast(acc[nt][mt][4 * g + 3]);
        i32x2 w;
        w[0] = (int)pkh2(v0, v1);
        w[1] = (int)pkh2(v2, v3);
        *(i32x2*)(hi + swzb(m * 512 + n * 2, m)) = w;
        float l0 = (v0 - (float)(_Float16)v0) * S11;
        float l1 = (v1 - (float)(_Float16)v1) * S11;
        float l2 = (v2 - (float)(_Float16)v2) * S11;
        float l3 = (v3 - (float)(_Float16)v3) * S11;
        *(int*)(lo + swzb(m * 256 + n, m)) = pk4fp8(l0, l1, l2, l3);
      }
    }
}

// encoder: relu(acc) hi fp16 (@hi) + lo*ls fp16 (@lo), both RS512
DEV void write_h16(char* hi, char* lo, f32x16 acc[2][2], int lane, int nbase, float ls) {
  const int mr = lane & 31, hh = lane >> 5;
#pragma unroll
  for (int nt = 0; nt < 2; ++nt)
#pragma unroll
    for (int mt = 0; mt < 2; ++mt) {
      int m = mt * 32 + mr;
#pragma unroll
      for (int g = 0; g < 4; ++g) {
        int n = nbase + nt * 32 + 8 * g + 4 * hh;
        float v0 = fmaxf(acc[nt][mt][4 * g + 0], 0.f);
        float v1 = fmaxf(acc[nt][mt][4 * g + 1], 0.f);
        float v2 = fmaxf(acc[nt][mt][4 * g + 2], 0.f);
        float v3 = fmaxf(acc[nt][mt][4 * g + 3], 0.f);
        i32x2 w;
        w[0] = (int)pkh2(v0, v1); w[1] = (int)pkh2(v2, v3);
        *(i32x2*)(hi + swzb(m * 512 + n * 2, m)) = w;
        w[0] = (int)pkh2((v0 - (float)(_Float16)v0) * ls, (v1 - (float)(_Float16)v1) * ls);
        w[1] = (int)pkh2((v2 - (float)(_Float16)v2) * ls, (v3 - (float)(_Float16)v3) * ls);
        *(i32x2*)(lo + swzb(m * 512 + n * 2, m)) = w;
      }
    }
}

// classifier: relu(acc) hi fp16 only
DEV void write_hc(char* hi, f32x16 acc[2][2], int lane, int nbase) {
  const int mr = lane & 31, hh = lane >> 5;
#pragma unroll
  for (int nt = 0; nt < 2; ++nt)
#pragma unroll
    for (int mt = 0; mt < 2; ++mt) {
      int m = mt * 32 + mr;
#pragma unroll
      for (int g = 0; g < 4; ++g) {
        int n = nbase + nt * 32 + 8 * g + 4 * hh;
        i32x2 w;
        w[0] = (int)pkh2(fmaxf(acc[nt][mt][4 * g + 0], 0.f), fmaxf(acc[nt][mt][4 * g + 1], 0.f));
        w[1] = (int)pkh2(fmaxf(acc[nt][mt][4 * g + 2], 0.f), fmaxf(acc[nt][mt][4 * g + 3], 0.f));
        *(i32x2*)(hi + swzb(m * 512 + n * 2, m)) = w;
      }
    }
}

// fp32 D[n][m] -> f layout [64][128]f32 RS512 @ACT
DEV void write_f32v(char* dst, const f32x16& a0, const f32x16& a1, int lane, int nbase) {
  const int mr = lane & 31, hh = lane >> 5;
#pragma unroll
  for (int mt = 0; mt < 2; ++mt) {
    const f32x16& a = mt ? a1 : a0;
    int m = mt * 32 + mr;
#pragma unroll
    for (int g = 0; g < 4; ++g) {
      int n = nbase + 8 * g + 4 * hh;
      f32x4 v = { a[4 * g + 0], a[4 * g + 1], a[4 * g + 2], a[4 * g + 3] };
      *(f32x4*)(dst + swzb(m * 512 + n * 4, m)) = v;
    }
  }
}

DEV void read_kv(const char* sm, int m, int cs, float* kv) {
#pragma unroll
  for (int blk = 0; blk < 8; ++blk) {
    f32x4 v = *(const f32x4*)(sm + ACT + swzb(m * 512 + cs * 128 + blk * 16, m));
    kv[4 * blk] = v[0]; kv[4 * blk + 1] = v[1]; kv[4 * blk + 2] = v[2]; kv[4 * blk + 3] = v[3];
  }
}

// owners: write 8 staged values: hi fp16 @ACT, lo*32 fp16 @SLO
DEV void write_stage8(char* sm, int m, int cs, int gg, const float* sv) {
  i32x4 wh, wl;
#pragma unroll
  for (int j = 0; j < 4; ++j) {
    float v0 = sv[2 * j], v1 = sv[2 * j + 1];
    _Float16 h0 = (_Float16)v0, h1 = (_Float16)v1;
    f16x2 ph = { h0, h1 };
    f16x2 pl = { (_Float16)((v0 - (float)h0) * S5), (_Float16)((v1 - (float)h1) * S5) };
    wh[j] = __builtin_bit_cast(int, ph);
    wl[j] = __builtin_bit_cast(int, pl);
  }
  int off = swzb(m * 256 + cs * 64 + gg * 16, m);
  *(i32x4*)(sm + ACT + off) = wh;
  *(i32x4*)(sm + SLO + off) = wl;
}

// ---- one MLP eval: s (ACT/SLO) -> f (ACT, fp32). W2/W3 hi streamed from global. ----
DEV void f_eval(char* sm, const f16x8* wsW1, float t,
                const f16x8* W1h, const f16x8* Au,
                const float* __restrict__ W2, const float* __restrict__ W3,
                int lane, int wave) {
  const int mr = lane & 31, kh = (lane >> 5) * 8, hh = lane >> 5;
  const int wb64 = wave * 64, wb32 = wave * 32;

  __syncthreads();  // A: stage visible
  f32x16 a1[2][2];
#pragma unroll
  for (int nt = 0; nt < 2; ++nt)
#pragma unroll
    for (int mt = 0; mt < 2; ++mt)
#pragma unroll
      for (int r = 0; r < 16; ++r) a1[nt][mt][r] = 0.f;

  // W1_lo stream (values *256 fp16, frag table in d_ws), depth-2 rolling buffer
  const f16x8* wp = wsW1 + (size_t)wave * 1024 + lane;   // + (nt*512 + ks*64)
  f16x8 wq[2][2];
  wq[0][0] = wp[0];   wq[0][1] = wp[512];
  wq[1][0] = wp[64];  wq[1][1] = wp[512 + 64];
#pragma unroll
  for (int ks = 0; ks < 8; ++ks) {
    f16x8 wl0 = wq[ks & 1][0], wl1 = wq[ks & 1][1];
    if (ks + 2 < 8) {
      wq[ks & 1][0] = wp[(ks + 2) * 64];
      wq[ks & 1][1] = wp[512 + (ks + 2) * 64];
    }
    int ke = ks * 16 + kh;
    f16x8 bh0 = read_f16t(sm + ACT, 256, mr, ke);
    f16x8 bh1 = read_f16t(sm + ACT, 256, 32 + mr, ke);
    f16x8 bl0 = read_f16t(sm + SLO, 256, mr, ke);       // s_lo*32
    f16x8 bl1 = read_f16t(sm + SLO, 256, 32 + mr, ke);
    f16x8 bh0m = mulh(bh0, IS8), bh1m = mulh(bh1, IS8); // for W1_lo(*256) term
    f16x8 w1s0 = mulh(W1h[ks], IS5), w1s1 = mulh(W1h[8 + ks], IS5);
    // term1: s_hi @ W1_hi
    a1[0][0] = MFMA16(W1h[ks],     bh0, a1[0][0]);
    a1[0][1] = MFMA16(W1h[ks],     bh1, a1[0][1]);
    a1[1][0] = MFMA16(W1h[8 + ks], bh0, a1[1][0]);
    a1[1][1] = MFMA16(W1h[8 + ks], bh1, a1[1][1]);
    // term2: (s_lo*32) @ (W1_hi/32)
    a1[0][0] = MFMA16(w1s0, bl0, a1[0][0]);
    a1[0][1] = MFMA16(w1s0, bl1, a1[0][1]);
    a1[1][0] = MFMA16(w1s1, bl0, a1[1][0]);
    a1[1][1] = MFMA16(w1s1, bl1, a1[1][1]);
    // term3: (s_hi/256) @ (W1_lo*256)
    a1[0][0] = MFMA16(wl0, bh0m, a1[0][0]);
    a1[0][1] = MFMA16(wl0, bh1m, a1[0][1]);
    a1[1][0] = MFMA16(wl1, bh0m, a1[1][0]);
    a1[1][1] = MFMA16(wl1, bh1m, a1[1][1]);
  }
  // U-slice: U0 + t*U1 at ~fp32 (lo slots pre-scaled *256)
  {
    _Float16 th = (_Float16)t;
    _Float16 tl = (_Float16)(t - (float)th);
    f16x8 ub, ul;
#pragma unroll
    for (int j = 0; j < 8; ++j) { ub[j] = (_Float16)0.f; ul[j] = (_Float16)0.f; }
    if (kh == 0) {
      ub[0] = (_Float16)1.0f; ub[1] = th;
      ub[2] = (_Float16)IS8;  ub[3] = (_Float16)((float)th * IS8);
      ul[1] = tl;             ul[3] = (_Float16)((float)tl * IS8);
    }
#pragma unroll
    for (int nt = 0; nt < 2; ++nt) {
      a1[nt][0] = MFMA16(Au[nt], ub, a1[nt][0]);
      a1[nt][1] = MFMA16(Au[nt], ub, a1[nt][1]);
      a1[nt][0] = MFMA16(Au[nt], ul, a1[nt][0]);
      a1[nt][1] = MFMA16(Au[nt], ul, a1[nt][1]);
    }
  }
  __syncthreads();  // G1: s reads done
  write_h8(sm + ACT, sm + ALO, a1, lane, wb64);
  __syncthreads();  // C: h1 ready

  // ---- layer 2 (W2 hi streamed from global f32, depth-2 prefetch) ----
  const float* B2p = (const float*)(sm + B2O);
  f32x16 a2[2][2];
#pragma unroll
  for (int nt = 0; nt < 2; ++nt)
#pragma unroll
    for (int g = 0; g < 4; ++g) {
      int n = wb64 + nt * 32 + 8 * g + 4 * hh;
      f32x4 bv = *(const f32x4*)(B2p + n);
#pragma unroll
      for (int r = 0; r < 4; ++r) { a2[nt][0][4 * g + r] = bv[r]; a2[nt][1][4 * g + r] = bv[r]; }
    }
  const float* w2r0 = W2 + (size_t)(wb64 + mr) * 256 + kh;
  const float* w2r1 = W2 + (size_t)(wb64 + 32 + mr) * 256 + kh;
  f32x4 w2b[2][2][2];   // [slot][nt][half]
#pragma unroll
  for (int s = 0; s < 2; ++s) {
    w2b[s][0][0] = *(const f32x4*)(w2r0 + s * 16);
    w2b[s][0][1] = *(const f32x4*)(w2r0 + s * 16 + 4);
    w2b[s][1][0] = *(const f32x4*)(w2r1 + s * 16);
    w2b[s][1][1] = *(const f32x4*)(w2r1 + s * 16 + 4);
  }
#pragma unroll
  for (int ks = 0; ks < 16; ++ks) {
    f16x8 W2h0 = cvt8v(w2b[ks & 1][0][0], w2b[ks & 1][0][1]);
    f16x8 W2h1 = cvt8v(w2b[ks & 1][1][0], w2b[ks & 1][1][1]);
    if (ks + 2 < 16) {
      w2b[ks & 1][0][0] = *(const f32x4*)(w2r0 + (ks + 2) * 16);
      w2b[ks & 1][0][1] = *(const f32x4*)(w2r0 + (ks + 2) * 16 + 4);
      w2b[ks & 1][1][0] = *(const f32x4*)(w2r1 + (ks + 2) * 16);
      w2b[ks & 1][1][1] = *(const f32x4*)(w2r1 + (ks + 2) * 16 + 4);
    }
    int ke = ks * 16 + kh;
    f16x8 bh0 = read_f16t(sm + ACT, 512, mr, ke);
    f16x8 bh1 = read_f16t(sm + ACT, 512, 32 + mr, ke);
    f16x8 bl0 = dec8(read8b(sm + ALO, mr, ke), IS6);      // h1_lo*32
    f16x8 bl1 = dec8(read8b(sm + ALO, 32 + mr, ke), IS6);
    f16x8 w2s0 = mulh(W2h0, IS5), w2s1 = mulh(W2h1, IS5);
    f16x8 bh0m = mulh(bh0, IS6), bh1m = mulh(bh1, IS6);
    i32x2 t0 = *(const i32x2*)(sm + W2L + ((size_t)((wave * 2 + 0) * 16 + ks) * 64 + lane) * 8);
    i32x2 t1 = *(const i32x2*)(sm + W2L + ((size_t)((wave * 2 + 1) * 16 + ks) * 64 + lane) * 8);
    f16x8 wa0 = dec8(t0, IS5), wa1 = dec8(t1, IS5);       // W2_lo*64
    a2[0][0] = MFMA16(W2h0, bh0, a2[0][0]);
    a2[0][1] = MFMA16(W2h0, bh1, a2[0][1]);
    a2[1][0] = MFMA16(W2h1, bh0, a2[1][0]);
    a2[1][1] = MFMA16(W2h1, bh1, a2[1][1]);
    a2[0][0] = MFMA16(w2s0, bl0, a2[0][0]);
    a2[0][1] = MFMA16(w2s0, bl1, a2[0][1]);
    a2[1][0] = MFMA16(w2s1, bl0, a2[1][0]);
    a2[1][1] = MFMA16(w2s1, bl1, a2[1][1]);
    a2[0][0] = MFMA16(wa0, bh0m, a2[0][0]);
    a2[0][1] = MFMA16(wa0, bh1m, a2[0][1]);
    a2[1][0] = MFMA16(wa1, bh0m, a2[1][0]);
    a2[1][1] = MFMA16(wa1, bh1m, a2[1][1]);
  }
  __syncthreads();  // G2: h1 reads done
  write_h8(sm + ACT, sm + ALO, a2, lane, wb64);
  __syncthreads();  // E: h2 ready

  // ---- layer 3 (W3 hi streamed from global f32, depth-2 prefetch) ----
  const float* B3p = (const float*)(sm + B3O);
  f32x16 a30, a31;
#pragma unroll
  for (int g = 0; g < 4; ++g) {
    int n = wb32 + 8 * g + 4 * hh;
    f32x4 bv = *(const f32x4*)(B3p + n);
#pragma unroll
    for (int r = 0; r < 4; ++r) { a30[4 * g + r] = bv[r]; a31[4 * g + r] = bv[r]; }
  }
  const float* w3r = W3 + (size_t)(wb32 + mr) * 256 + kh;
  f32x4 w3b[2][2];   // [slot][half]
#pragma unroll
  for (int s = 0; s < 2; ++s) {
    w3b[s][0] = *(const f32x4*)(w3r + s * 16);
    w3b[s][1] = *(const f32x4*)(w3r + s * 16 + 4);
  }
#pragma unroll
  for (int ks = 0; ks < 16; ++ks) {
    f16x8 W3h = cvt8v(w3b[ks & 1][0], w3b[ks & 1][1]);
    if (ks + 2 < 16) {
      w3b[ks & 1][0] = *(const f32x4*)(w3r + (ks + 2) * 16);
      w3b[ks & 1][1] = *(const f32x4*)(w3r + (ks + 2) * 16 + 4);
    }
    int ke = ks * 16 + kh;
    f16x8 bh0 = read_f16t(sm + ACT, 512, mr, ke);
    f16x8 bh1 = read_f16t(sm + ACT, 512, 32 + mr, ke);
    f16x8 bl0 = dec8(read8b(sm + ALO, mr, ke), IS6);
    f16x8 bl1 = dec8(read8b(sm + ALO, 32 + mr, ke), IS6);
    f16x8 w3s = mulh(W3h, IS5);
    f16x8 bh0m = mulh(bh0, IS6), bh1m = mulh(bh1, IS6);
    i32x2 t0 = *(const i32x2*)(sm + W3L + ((size_t)(wave * 16 + ks) * 64 + lane) * 8);
    f16x8 wa = dec8(t0, IS5);
    a30 = MFMA16(W3h, bh0, a30);
    a31 = MFMA16(W3h, bh1, a31);
    a30 = MFMA16(w3s, bl0, a30);
    a31 = MFMA16(w3s, bl1, a31);
    a30 = MFMA16(wa, bh0m, a30);
    a31 = MFMA16(wa, bh1m, a31);
  }
  __syncthreads();  // G3: h2 reads done
  write_f32v(sm + ACT, a30, a31, lane, wb32);
  __syncthreads();  // F: f ready
}

__global__ void prep_w1lo(const float* __restrict__ W1, _Float16* __restrict__ ws) {
  int i = blockIdx.x * 256 + threadIdx.x;   // 0..4095 frags
  int lane = i & 63, ks = (i >> 6) & 7, nt = (i >> 9) & 1, wave = (i >> 10) & 3;
  int row = wave * 64 + nt * 32 + (lane & 31);
  int col = ks * 16 + (lane >> 5) * 8;
  const float* p = W1 + (size_t)row * 128 + col;
  _Float16* o = ws + (size_t)i * 8;
#pragma unroll
  for (int j = 0; j < 8; ++j) {
    float w = p[j];
    _Float16 h = (_Float16)w;
    o[j] = (_Float16)((w - (float)h) * S8);
  }
}

__global__ __launch_bounds__(256, 1) void node_kernel(
    const float* __restrict__ traj,
    const float* __restrict__ We1, const float* __restrict__ be1,
    const float* __restrict__ We2, const float* __restrict__ be2,
    const float* __restrict__ wte, const float* __restrict__ bte,
    const float* __restrict__ W1,  const float* __restrict__ b1,
    const float* __restrict__ W2,  const float* __restrict__ b2,
    const float* __restrict__ W3,  const float* __restrict__ b3,
    const float* __restrict__ Wc1, const float* __restrict__ bc1,
    const float* __restrict__ Wc2, const float* __restrict__ bc2,
    const _Float16* __restrict__ wsW1h, float* __restrict__ out) {
  __shared__ __align__(16) char sm[SMEM_BYTES];
  const int tid  = threadIdx.x;
  const int lane = tid & 63, wave = tid >> 6;
  const int mr = lane & 31, kh = (lane >> 5) * 8, hh = lane >> 5;
  const int wb64 = wave * 64, wb32 = wave * 32;
  const int brow = blockIdx.x * 64;
  const f16x8* wsW1 = (const f16x8*)wsW1h;

  // ---- init: U0/U1 fold, bias tables ----
  {
    int n = tid;
    float u0 = b1[n], u1 = 0.f;
    const float* wr = W1 + n * 128;
    for (int k = 0; k < 128; ++k) { float w = wr[k]; u1 += wte[k] * w; u0 += bte[k] * w; }
    float* U = (float*)(sm + U01O);
    U[2 * n] = u0; U[2 * n + 1] = u1;
    ((float*)(sm + B2O))[n] = b2[n];
    if (n < 128) ((float*)(sm + B3O))[n] = b3[n];
  }

  // ---- resident hi fragments: W1 only ----
  f16x8 W1h[16], Au[2];
#pragma unroll
  for (int nt = 0; nt < 2; ++nt)
#pragma unroll
    for (int ks = 0; ks < 8; ++ks)
      W1h[nt * 8 + ks] = cvt_h(W1 + (size_t)(wb64 + nt * 32 + mr) * 128 + ks * 16 + kh);

  __syncthreads();  // U01 ready

  // Au: rows n, slots [U0h, U1h, U0l*256, U1l*256]
#pragma unroll
  for (int nt = 0; nt < 2; ++nt) {
    f16x8 a;
#pragma unroll
    for (int j = 0; j < 8; ++j) a[j] = (_Float16)0.f;
    if (kh == 0) {
      const float* U = (const float*)(sm + U01O);
      int n = wb64 + nt * 32 + mr;
      float u0 = U[2 * n], u1 = U[2 * n + 1];
      _Float16 u0h = (_Float16)u0, u1h = (_Float16)u1;
      a[0] = u0h; a[1] = u1h;
      a[2] = (_Float16)((u0 - (float)u0h) * S8);
      a[3] = (_Float16)((u1 - (float)u1h) * S8);
    }
    Au[nt] = a;
  }

  const int m_own = tid >> 2, cs = tid & 3;

  // ---- encoder ----
  f32x16 ae[2][2];
#pragma unroll
  for (int nt = 0; nt < 2; ++nt)
#pragma unroll
    for (int mt = 0; mt < 2; ++mt)
#pragma unroll
      for (int r = 0; r < 16; ++r) ae[nt][mt][r] = 0.f;

  for (int c = 0; c < 3; ++c) {
    // stage x chunk: hi@ACT [64][256]f16, lo*64@W2L(scratch)
#pragma unroll
    for (int g = 0; g < 8; ++g) {
      const float* xp = traj + (size_t)(brow + m_own) * 7168 + c * 256 + cs * 64 + g * 8;
      f32x4 a = *(const f32x4*)xp;
      f32x4 b = *(const f32x4*)(xp + 4);
      i32x4 wh, wl;
#pragma unroll
      for (int j = 0; j < 2; ++j) {
        float v0 = a[2 * j], v1 = a[2 * j + 1];
        _Float16 h0 = (_Float16)v0, h1 = (_Float16)v1;
        f16x2 ph = { h0, h1 };
        f16x2 pl = { (_Float16)((v0 - (float)h0) * S6), (_Float16)((v1 - (float)h1) * S6) };
        wh[j] = __builtin_bit_cast(int, ph); wl[j] = __builtin_bit_cast(int, pl);
        float w0 = b[2 * j], w1 = b[2 * j + 1];
        _Float16 g0 = (_Float16)w0, g1 = (_Float16)w1;
        f16x2 qh = { g0, g1 };
        f16x2 ql = { (_Float16)((w0 - (float)g0) * S6), (_Float16)((w1 - (float)g1) * S6) };
        wh[2 + j] = __builtin_bit_cast(int, qh); wl[2 + j] = __builtin_bit_cast(int, ql);
      }
      int off = swzb(m_own * 512 + cs * 128 + g * 16, m_own);
      *(i32x4*)(sm + ACT + off) = wh;
      *(i32x4*)(sm + W2L + off) = wl;
    }
    __syncthreads();
#pragma unroll
    for (int ks = 0; ks < 16; ++ks) {
      int ke = ks * 16 + kh;
      f16x8 bh0 = read_f16t(sm + ACT, 512, mr, ke);
      f16x8 bh1 = read_f16t(sm + ACT, 512, 32 + mr, ke);
      f16x8 bl0 = read_f16t(sm + W2L, 512, mr, ke);
      f16x8 bl1 = read_f16t(sm + W2L, 512, 32 + mr, ke);
      f16x8 bh0m = mulh(bh0, IS6), bh1m = mulh(bh1, IS6);
#pragma unroll
      for (int nt = 0; nt < 2; ++nt) {
        f16x8 wh, wl;
        cvt_hl_s(We1 + (size_t)(wb64 + nt * 32 + mr) * 768 + c * 256 + ks * 16 + kh, wh, wl, S6);
        f16x8 whs = mulh(wh, IS6);
        ae[nt][0] = MFMA16(wh, bh0, ae[nt][0]);
        ae[nt][1] = MFMA16(wh, bh1, ae[nt][1]);
        ae[nt][0] = MFMA16(whs, bl0, ae[nt][0]);
        ae[nt][1] = MFMA16(whs, bl1, ae[nt][1]);
        ae[nt][0] = MFMA16(wl, bh0m, ae[nt][0]);
        ae[nt][1] = MFMA16(wl, bh1m, ae[nt][1]);
      }
    }
    __syncthreads();
  }
#pragma unroll
  for (int nt = 0; nt < 2; ++nt)
#pragma unroll
    for (int r = 0; r < 16; ++r) {
      int n = wb64 + nt * 32 + (r & 3) + 8 * (r >> 2) + 4 * hh;
      float bv = be1[n];
      ae[nt][0][r] += bv; ae[nt][1][r] += bv;
    }
  write_h16(sm + ACT, sm + W2L, ae, lane, wb64, S6);   // h_enc hi@ACT, lo*64@W2L
  __syncthreads();

  {
    f32x16 az0, az1;
#pragma unroll
    for (int r = 0; r < 16; ++r) { az0[r] = 0.f; az1[r] = 0.f; }
#pragma unroll
    for (int ks = 0; ks < 16; ++ks) {
      int ke = ks * 16 + kh;
      f16x8 bh0 = read_f16t(sm + ACT, 512, mr, ke);
      f16x8 bh1 = read_f16t(sm + ACT, 512, 32 + mr, ke);
      f16x8 bl0 = read_f16t(sm + W2L, 512, mr, ke);
      f16x8 bl1 = read_f16t(sm + W2L, 512, 32 + mr, ke);
      f16x8 bh0m = mulh(bh0, IS6), bh1m = mulh(bh1, IS6);
      f16x8 wh, wl;
      cvt_hl_s(We2 + (size_t)(wb32 + mr) * 256 + ks * 16 + kh, wh, wl, S6);
      f16x8 whs = mulh(wh, IS6);
      az0 = MFMA16(wh, bh0, az0);
      az1 = MFMA16(wh, bh1, az1);
      az0 = MFMA16(whs, bl0, az0);
      az1 = MFMA16(whs, bl1, az1);
      az0 = MFMA16(wl, bh0m, az0);
      az1 = MFMA16(wl, bh1m, az1);
    }
#pragma unroll
    for (int r = 0; r < 16; ++r) {
      int n = wb32 + (r & 3) + 8 * (r >> 2) + 4 * hh;
      float bv = be2[n];
      az0[r] += bv; az1[r] += bv;
    }
    __syncthreads();                    // h_enc reads done
    write_f32v(sm + ACT, az0, az1, lane, wb32);  // z0 in f layout
    __syncthreads();
  }

  // ---- owners pick up z0; write frame 0 ----
  float z[32], Acc[32], k1v[32], kv[32];
  read_kv(sm, m_own, cs, z);
  float* outz = out + 16384;
  {
    float* p = outz + (size_t)(brow + m_own) * 128 + cs * 32;
#pragma unroll
    for (int g = 0; g < 8; ++g) {
      f32x4 v = { z[4 * g], z[4 * g + 1], z[4 * g + 2], z[4 * g + 3] };
      *(f32x4*)(p + 4 * g) = v;
    }
  }

  // ---- fill W2_lo / W3_lo fp8 tables (*2048) ----
#pragma unroll
  for (int nt = 0; nt < 2; ++nt)
    for (int ks = 0; ks < 16; ++ks) {
      const float* p = W2 + (size_t)(wb64 + nt * 32 + mr) * 256 + ks * 16 + kh;
      float l[8];
#pragma unroll
      for (int j = 0; j < 8; ++j) { float w = p[j]; l[j] = (w - (float)(_Float16)w) * S11; }
      i32x2 wv;
      wv[0] = pk4fp8(l[0], l[1], l[2], l[3]);
      wv[1] = pk4fp8(l[4], l[5], l[6], l[7]);
      *(i32x2*)(sm + W2L + ((size_t)((wave * 2 + nt) * 16 + ks) * 64 + lane) * 8) = wv;
    }
  for (int ks = 0; ks < 16; ++ks) {
    const float* p = W3 + (size_t)(wb32 + mr) * 256 + ks * 16 + kh;
    float l[8];
#pragma unroll
    for (int j = 0; j < 8; ++j) { float w = p[j]; l[j] = (w - (float)(_Float16)w) * S11; }
    i32x2 wv;
    wv[0] = pk4fp8(l[0], l[1], l[2], l[3]);
    wv[1] = pk4fp8(l[4], l[5], l[6], l[7]);
    *(i32x2*)(sm + W3L + ((size_t)(wave * 16 + ks) * 64 + lane) * 8) = wv;
  }

  // ---- RK4 (3/8 rule), 54 steps ----
  for (int st = 0; st < 54; ++st) {
    float t0 = st * 0.5f;
    __syncthreads();  // H: f/z0 reads done; tables ready (st==0)
#pragma unroll
    for (int gg = 0; gg < 4; ++gg) write_stage8(sm, m_own, cs, gg, z + 8 * gg);  // s1 = z
    f_eval(sm, wsW1, t0, W1h, Au, W2, W3, lane, wave);          // k1
    read_kv(sm, m_own, cs, kv);
    __syncthreads();
#pragma unroll
    for (int gg = 0; gg < 4; ++gg) {
      float sv[8];
#pragma unroll
      for (int i = 0; i < 8; ++i) {
        int e = 8 * gg + i;
        Acc[e] = z[e] + DT8 * kv[e];
        sv[i] = z[e] + DT3 * kv[e];
        k1v[e] = kv[e];
      }
      write_stage8(sm, m_own, cs, gg, sv);
    }
    f_eval(sm, wsW1, t0 + DT3, W1h, Au, W2, W3, lane, wave);    // k2
    read_kv(sm, m_own, cs, kv);
    __syncthreads();
#pragma unroll
    for (int gg = 0; gg < 4; ++gg) {
      float sv[8];
#pragma unroll
      for (int i = 0; i < 8; ++i) {
        int e = 8 * gg + i;
        Acc[e] += 3.0f * DT8 * kv[e];
        sv[i] = z[e] + DT * kv[e] - DT3 * k1v[e];
        k1v[e] = k1v[e] - kv[e];   // d12
      }
      write_stage8(sm, m_own, cs, gg, sv);
    }
    f_eval(sm, wsW1, t0 + DT23, W1h, Au, W2, W3, lane, wave);   // k3
    read_kv(sm, m_own, cs, kv);
    __syncthreads();
#pragma unroll
    for (int gg = 0; gg < 4; ++gg) {
      float sv[8];
#pragma unroll
      for (int i = 0; i < 8; ++i) {
        int e = 8 * gg + i;
        Acc[e] += 3.0f * DT8 * kv[e];
        sv[i] = z[e] + DT * (k1v[e] + kv[e]);
      }
      write_stage8(sm, m_own, cs, gg, sv);
    }
    f_eval(sm, wsW1, t0 + DT, W1h, Au, W2, W3, lane, wave);     // k4
    read_kv(sm, m_own, cs, kv);
#pragma unroll
    for (int e = 0; e < 32; ++e) z[e] = Acc[e] + DT8 * kv[e];
    if (st & 1) {
      int frame = (st >> 1) + 1;
      float* p = outz + (size_t)frame * 2097152 + (size_t)(brow + m_own) * 128 + cs * 32;
#pragma unroll
      for (int g = 0; g < 8; ++g) {
        f32x4 v = { z[4 * g], z[4 * g + 1], z[4 * g + 2], z[4 * g + 3] };
        *(f32x4*)(p + 4 * g) = v;
      }
    }
  }

  // ---- classifier ----
  __syncthreads();  // f reads done
#pragma unroll
  for (int gg = 0; gg < 4; ++gg) write_stage8(sm, m_own, cs, gg, z + 8 * gg);
  __syncthreads();
  f32x16 ac[2][2];
#pragma unroll
  for (int nt = 0; nt < 2; ++nt)
#pragma unroll
    for (int r = 0; r < 16; ++r) {
      int n = wb64 + nt * 32 + (r & 3) + 8 * (r >> 2) + 4 * hh;
      float bv = bc1[n];
      ac[nt][0][r] = bv; ac[nt][1][r] = bv;
    }
#pragma unroll
  for (int ks = 0; ks < 8; ++ks) {
    int ke = ks * 16 + kh;
    f16x8 bh0 = read_f16t(sm + ACT, 256, mr, ke);
    f16x8 bh1 = read_f16t(sm + ACT, 256, 32 + mr, ke);
    f16x8 bl0 = read_f16t(sm + SLO, 256, mr, ke);     // zL_lo*32
    f16x8 bl1 = read_f16t(sm + SLO, 256, 32 + mr, ke);
#pragma unroll
    for (int nt = 0; nt < 2; ++nt) {
      f16x8 wh, wl;
      cvt_hl_s(Wc1 + (size_t)(wb64 + nt * 32 + mr) * 128 + ks * 16 + kh, wh, wl, 1.0f);
      f16x8 whs = mulh(wh, IS5);
      ac[nt][0] = MFMA16(wh, bh0, ac[nt][0]);
      ac[nt][1] = MFMA16(wh, bh1, ac[nt][1]);
      ac[nt][0] = MFMA16(whs, bl0, ac[nt][0]);
      ac[nt][1] = MFMA16(whs, bl1, ac[nt][1]);
      ac[nt][0] = MFMA16(wl, bh0, ac[nt][0]);
      ac[nt][1] = MFMA16(wl, bh1, ac[nt][1]);
    }
  }
  __syncthreads();  // s reads done
  write_hc(sm + ACT, ac, lane, wb64);
  __syncthreads();
  if (tid < 64) {
    float acc = bc2[0];
#pragma unroll 8
    for (int c0 = 0; c0 < 256; c0 += 8) {
      f16x8 hv = read_f16t(sm + ACT, 512, tid, c0);
#pragma unroll
      for (int j = 0; j < 8; ++j) acc += (float)hv[j] * Wc2[c0 + j];
    }
    out[brow + tid] = __builtin_amdgcn_rcpf(1.0f + __builtin_amdgcn_exp2f(-acc * 1.442695041f));
  }
}

extern "C" void kernel_launch(void* const* d_in, const int* in_sizes, int n_in,
                              void* d_out, int out_size, void* d_ws, size_t ws_size,
                              hipStream_t stream) {
  (void)in_sizes; (void)n_in; (void)out_size; (void)ws_size;
  const float* traj = (const float*)d_in[0];
  const float* We1  = (const float*)d_in[1];
  const float* be1  = (const float*)d_in[2];
  const float* We2  = (const float*)d_in[3];
  const float* be2  = (const float*)d_in[4];
  const float* wte  = (const float*)d_in[5];
  const float* bte  = (const float*)d_in[6];
  const float* W1   = (const float*)d_in[7];
  const float* b1   = (const float*)d_in[8];
  const float* W2   = (const float*)d_in[9];
  const float* b2   = (const float*)d_in[10];
  const float* W3   = (const float*)d_in[11];
  const float* b3   = (const float*)d_in[12];
  const float* Wc1  = (const float*)d_in[13];
  const float* bc1  = (const float*)d_in[14];
  const float* Wc2  = (const float*)d_in[15];
  const float* bc2  = (const float*)d_in[16];
  _Float16* wsW1 = (_Float16*)d_ws;
  hipLaunchKernelGGL(prep_w1lo, dim3(16), dim3(256), 0, stream, W1, wsW1);
  hipLaunchKernelGGL(node_kernel, dim3(256), dim3(256), 0, stream,
                     traj, We1, be1, We2, be2, wte, bte, W1, b1, W2, b2, W3, b3,
                     Wc1, bc1, Wc2, bc2, (const _Float16*)wsW1, (float*)d_out);
}